// Round 16
// baseline (59.967 us; speedup 1.0000x reference)
//
#include <hip/hip_runtime.h>

// Deformable Conv2D, MFMA — producer/consumer wave specialization.
// x(8,64,96,96) f32, offset(8,18,96,96) f32, W(64,64,3,3) f32 -> out(8,64,96,96) f32.
// prep_all (XCD-pinned): xt = bf16 NHWC padded [8][98][98][64]; Bt = bf16 B-fragments.
// deform_mfma: 1152 blocks x 512 thr (8 waves). Waves 0-3 = producers: params (in-reg
//   shuffle, R15-verified) + coalesced corner gathers (R10 map, 8 lines/instr) + combine
//   -> sA[n&1] (R10 write map). Waves 4-7 = consumers: B-stationary MFMA (R10 mfma_tap,
//   o-tile = w-4, 2 Bt loads/tap). One uniform barrier/tap; dbuf sA => WAR pairs are
//   2 barriers apart. Per-tap critical path = max(producer, consumer), not the sum.

typedef __bf16 bf16_t;
typedef __bf16 bf16x8 __attribute__((ext_vector_type(8)));
typedef float  f32x4  __attribute__((ext_vector_type(4)));

#define NB 8
#define NC 64
#define NO 64
#define NH 96
#define NW 96
#define HP 98
#define NPT 9
#define PIX 64           // pixels per block
#define ASTR 72          // sA row stride in bf16

// ---------- parameter math (identical to round-0 verified version) ----------
struct DCParams { int u0, u1, v0, v1; float glt, grb, glb, grt; };

__device__ __forceinline__ DCParams dc_params(const float* __restrict__ off, int b, int i, int j, int n) {
    const int a = n / 3, b2 = n % 3;
    const float offx = off[((size_t)(b * 18 + n) * NH + i) * NW + j];
    const float offy = off[((size_t)(b * 18 + 9 + n) * NH + i) * NW + j];
    float px = (float)(i + a) + offx;
    float py = (float)(j + b2) + offy;
    const float fx = floorf(px), fy = floorf(py);
    const float x0 = fminf(fmaxf(fx, 0.f), 97.f);
    const float x1 = fminf(fmaxf(fx + 1.f, 0.f), 97.f);
    const float y0 = fminf(fmaxf(fy, 0.f), 97.f);
    const float y1 = fminf(fmaxf(fy + 1.f, 0.f), 97.f);
    px = (px < 1.f || px > 96.f) ? x0 : px;
    py = (py < 1.f || py > 96.f) ? y0 : py;
    const float wx0 = 1.f + x0 - px;
    const float wx1 = 1.f - x1 + px;
    const float wy0 = 1.f + y0 - py;
    const float wy1 = 1.f - y1 + py;
    DCParams p;
    p.u0 = (int)x0; p.u1 = (int)x1; p.v0 = (int)y0; p.v1 = (int)y1;
    p.glt = wx0 * wy0; p.grb = wx1 * wy1; p.glb = wx0 * wy1; p.grt = wx1 * wy0;
    return p;
}

// ---------- fused prep kernel (unchanged from R10, verified) ----------
__global__ __launch_bounds__(256) void prep_all(const float* __restrict__ x, const float* __restrict__ W,
                                                bf16_t* __restrict__ xt, bf16_t* __restrict__ Bt) {
    __shared__ float tile[64][17];
    const int blk = blockIdx.x;
    const int b = blk & 7;
    const int r = blk >> 3;
    const int t = threadIdx.x;

    if (r < 576) {                      // ---- interior fill (verified) ----
        const int jt = r % 6;
        const int i  = r / 6;
        const int j0 = jt * 16;
        {
            const int jj = t & 15, cq = t >> 4;
            #pragma unroll
            for (int rr = 0; rr < 4; ++rr) {
                const int c = cq * 4 + rr;
                tile[c][jj] = x[(((size_t)b * NC + c) * NH + i) * NW + j0 + jj];
            }
        }
        __syncthreads();
        {
            const int c = t & 63, jq = t >> 6;
            #pragma unroll
            for (int rr = 0; rr < 4; ++rr) {
                const int jj = jq * 4 + rr;
                xt[(((size_t)b * HP + (i + 1)) * HP + (j0 + jj + 1)) * NC + c] = (bf16_t)tile[c][jj];
            }
        }
    } else if (r < 592) {               // ---- border zero ----
        const int idx = (r - 576) * 256 + t;      // 0..4095; need 3104
        uint4* xt4 = (uint4*)xt;
        const size_t ib = (size_t)b * (HP * HP * NC / 8);
        const uint4 z = {0, 0, 0, 0};
        if (idx < 1568) {
            const int u   = (idx < 784) ? 0 : 97;
            const int pos = (idx < 784) ? idx : idx - 784;
            xt4[ib + (size_t)u * 784 + pos] = z;
        } else if (idx < 3104) {
            const int k  = idx - 1568;
            const int v  = (k < 768) ? 0 : 97;
            const int kk = (k < 768) ? k : k - 768;
            const int u  = 1 + (kk >> 3), c8 = kk & 7;
            xt4[ib + (size_t)(u * HP + v) * 8 + c8] = z;
        }
    } else if (b == 0) {                // ---- Bt build (verified) ----
        const int idx = (r - 592) * 256 + t;      // 0..4607
        const int l = idx & 63, frag = idx >> 6;
        const int nt = frag & 3, kk = (frag >> 2) & 1, n = frag >> 3;
        const int o  = nt * 16 + (l & 15);
        const int cb = kk * 32 + 8 * (l >> 4);
        bf16x8 v;
        #pragma unroll
        for (int j = 0; j < 8; ++j)
            v[j] = (bf16_t)W[(size_t)o * 576 + (cb + j) * 9 + n];
        *(bf16x8*)(Bt + (size_t)idx * 8) = v;
    }
}

// ---------- main kernel ----------
__device__ __forceinline__ void mfma_tap(const bf16_t* sAbuf, const bf16_t* __restrict__ Bt,
                                         int n, int w, int l, f32x4 acc[4]) {
    const int mrow = l & 15, khi = l >> 4;
    #pragma unroll
    for (int kk = 0; kk < 2; ++kk) {
        const bf16x8 bf = *(const bf16x8*)(Bt + (size_t)(((n * 2 + kk) * 4 + w)) * 512 + l * 8);
        #pragma unroll
        for (int mt = 0; mt < 4; ++mt) {
            const bf16x8 af = *(const bf16x8*)(sAbuf + (mt * 16 + mrow) * ASTR + kk * 32 + khi * 8);
            acc[mt] = __builtin_amdgcn_mfma_f32_16x16x32_bf16(af, bf, acc[mt], 0, 0, 0);
        }
    }
}

__global__ __launch_bounds__(512) void deform_mfma(const bf16_t* __restrict__ xt, const bf16_t* __restrict__ Bt,
                                                   const float* __restrict__ off, float* __restrict__ out) {
    // union: bf16 sA[2][64][72] (18432 B) main loop; f32 sO[64][68] (17408 B) epilogue
    __shared__ __align__(16) unsigned char smem[2 * PIX * ASTR * 2];
    bf16_t* sA = (bf16_t*)smem;
    float*  sO = (float*)smem;

    const int t = threadIdx.x;
    const int l = t & 63;        // lane
    const int w = t >> 6;        // wave 0..7
    const int bid = blockIdx.x;
    const int b  = bid & 7;      // one batch image per XCD
    const int pb = (bid >> 3) * PIX;

    const bool producer = (w < 4);
    const int pw = producer ? w : w - 4;   // producer: 16-px group; consumer: o-tile

    const int pl   = l >> 3;     // pixel-in-group low (0..7)
    const int slot = l & 7;      // channel slot
    const bf16_t* ibase = xt + (size_t)b * (HP * HP * NC) + slot * 8;

    f32x4 acc[4] = {};           // consumers only
    bf16x8 d[2][4];              // producers only: [q][corner]
    float4 gq0, gq1;

    // R15-verified: every lane computes dc_params for pixel (l&15) of group pw,
    // then shuffles pixel pl / pl+8 params into registers.
    auto compute_params = [&](int n, int4& a0, float4& g0, int4& a1, float4& g1) {
        const int pp = pb + pw * 16 + (l & 15);
        const int ii = pp / 96, jj = pp - (pp / 96) * 96;
        const DCParams p = dc_params(off, b, ii, jj, n);
        const int4   ai = make_int4((p.u0 * HP + p.v0) * NC, (p.u1 * HP + p.v1) * NC,
                                    (p.u0 * HP + p.v1) * NC, (p.u1 * HP + p.v0) * NC);
        const float4 gi = make_float4(p.glt, p.grb, p.glb, p.grt);
        a0.x = __shfl(ai.x, pl);     a0.y = __shfl(ai.y, pl);
        a0.z = __shfl(ai.z, pl);     a0.w = __shfl(ai.w, pl);
        g0.x = __shfl(gi.x, pl);     g0.y = __shfl(gi.y, pl);
        g0.z = __shfl(gi.z, pl);     g0.w = __shfl(gi.w, pl);
        a1.x = __shfl(ai.x, pl + 8); a1.y = __shfl(ai.y, pl + 8);
        a1.z = __shfl(ai.z, pl + 8); a1.w = __shfl(ai.w, pl + 8);
        g1.x = __shfl(gi.x, pl + 8); g1.y = __shfl(gi.y, pl + 8);
        g1.z = __shfl(gi.z, pl + 8); g1.w = __shfl(gi.w, pl + 8);
    };

    if (producer) {              // prologue: params + gather tap 0 (R10 verified map)
        int4 a0, a1;
        compute_params(0, a0, gq0, a1, gq1);
        d[0][0] = *(const bf16x8*)(ibase + a0.x);
        d[0][1] = *(const bf16x8*)(ibase + a0.y);
        d[0][2] = *(const bf16x8*)(ibase + a0.z);
        d[0][3] = *(const bf16x8*)(ibase + a0.w);
        d[1][0] = *(const bf16x8*)(ibase + a1.x);
        d[1][1] = *(const bf16x8*)(ibase + a1.y);
        d[1][2] = *(const bf16x8*)(ibase + a1.z);
        d[1][3] = *(const bf16x8*)(ibase + a1.w);
    }

    for (int n = 0; n < NPT; ++n) {
        bf16_t* buf = sA + (n & 1) * (PIX * ASTR);
        int4 a0n, a1n; float4 g0n, g1n;
        if (producer) {
            // combine in-register -> sA[n&1] rows pw*16+pl, pw*16+pl+8 (R10 write map)
            bf16x8 rv;
            #pragma unroll
            for (int e = 0; e < 8; ++e) {
                const float v = gq0.x * (float)d[0][0][e] + gq0.y * (float)d[0][1][e]
                              + gq0.z * (float)d[0][2][e] + gq0.w * (float)d[0][3][e];
                rv[e] = (bf16_t)v;
            }
            *(bf16x8*)(buf + (pw * 16 + pl) * ASTR + slot * 8) = rv;
            #pragma unroll
            for (int e = 0; e < 8; ++e) {
                const float v = gq1.x * (float)d[1][0][e] + gq1.y * (float)d[1][1][e]
                              + gq1.z * (float)d[1][2][e] + gq1.w * (float)d[1][3][e];
                rv[e] = (bf16_t)v;
            }
            *(bf16x8*)(buf + (pw * 16 + pl + 8) * ASTR + slot * 8) = rv;
            if (n + 1 < NPT) compute_params(n + 1, a0n, g0n, a1n, g1n);
        }
        __syncthreads();                     // uniform: sA[n&1] visible to consumers
        if (producer) {
            if (n + 1 < NPT) {               // issue next-tap gathers; retire under the
                d[0][0] = *(const bf16x8*)(ibase + a0n.x);   // CONSUMERS' MFMAs
                d[0][1] = *(const bf16x8*)(ibase + a0n.y);
                d[0][2] = *(const bf16x8*)(ibase + a0n.z);
                d[0][3] = *(const bf16x8*)(ibase + a0n.w);
                d[1][0] = *(const bf16x8*)(ibase + a1n.x);
                d[1][1] = *(const bf16x8*)(ibase + a1n.y);
                d[1][2] = *(const bf16x8*)(ibase + a1n.z);
                d[1][3] = *(const bf16x8*)(ibase + a1n.w);
                gq0 = g0n; gq1 = g1n;
            }
        } else {
            mfma_tap(buf, Bt, n, pw, l, acc);    // verified B-stationary MFMA
        }
    }

    __syncthreads();                             // consumers' final sA reads retired

    if (!producer) {                             // verified D-map writer (o-tile = pw)
        const int orow = pw * 16 + (l & 15);
        #pragma unroll
        for (int mt = 0; mt < 4; ++mt)
            #pragma unroll
            for (int r = 0; r < 4; ++r)
                sO[orow * 68 + mt * 16 + (l >> 4) * 4 + r] = acc[mt][r];
    }
    __syncthreads();

    if (t < 256) {                               // verified reader (byte-identical to R10)
        const int o = t >> 2, q = t & 3;
        float4* dst = (float4*)(out + ((size_t)(b * NO + o)) * (NH * NW) + pb + q * 16);
        const float* src = sO + o * 68 + q * 16;
        #pragma unroll
        for (int k2 = 0; k2 < 4; ++k2) dst[k2] = ((const float4*)src)[k2];
    }
}

// ---------- naive fallback (no workspace needed) ----------
__global__ __launch_bounds__(256) void deform_naive(const float* __restrict__ x, const float* __restrict__ W,
                                                    const float* __restrict__ off, float* __restrict__ out) {
    __shared__ float sv[576];
    __shared__ DCParams sp[NPT];
    const int t = threadIdx.x;
    const int P = blockIdx.x;
    const int b = P / (NH * NW), pp = P - b * (NH * NW);
    const int i = pp / 96, j = pp - (pp / 96) * 96;
    if (t < NPT) sp[t] = dc_params(off, b, i, j, t);
    __syncthreads();
    for (int k = t; k < 576; k += 256) {
        const int c = k / 9, n = k - c * 9;
        const DCParams p = sp[n];
        const float* xb = x + ((size_t)(b * NC + c)) * (NH * NW);
        const float vlt = (p.u0 >= 1 && p.u0 <= 96 && p.v0 >= 1 && p.v0 <= 96) ? xb[(p.u0 - 1) * 96 + (p.v0 - 1)] : 0.f;
        const float vrb = (p.u1 >= 1 && p.u1 <= 96 && p.v1 >= 1 && p.v1 <= 96) ? xb[(p.u1 - 1) * 96 + (p.v1 - 1)] : 0.f;
        const float vlb = (p.u0 >= 1 && p.u0 <= 96 && p.v1 >= 1 && p.v1 <= 96) ? xb[(p.u0 - 1) * 96 + (p.v1 - 1)] : 0.f;
        const float vrt = (p.u1 >= 1 && p.u1 <= 96 && p.v0 >= 1 && p.v0 <= 96) ? xb[(p.u1 - 1) * 96 + (p.v0 - 1)] : 0.f;
        sv[k] = p.glt * vlt + p.grb * vrb + p.glb * vlb + p.grt * vrt;
    }
    __syncthreads();
    if (t < NO) {
        const float* wrow = W + (size_t)t * 576;
        float acc = 0.f;
        for (int k = 0; k < 576; ++k) acc += sv[k] * wrow[k];
        out[((size_t)(b * NO + t)) * (NH * NW) + pp] = acc;
    }
}

extern "C" void kernel_launch(void* const* d_in, const int* in_sizes, int n_in,
                              void* d_out, int out_size, void* d_ws, size_t ws_size,
                              hipStream_t stream) {
    const float* x   = (const float*)d_in[0];
    const float* off = (const float*)d_in[1];
    const float* W   = (const float*)d_in[2];
    float* out = (float*)d_out;

    const size_t XT_ELEMS = (size_t)NB * HP * HP * NC;     // 4,917,248 bf16
    const size_t XT_BYTES = XT_ELEMS * 2;                  // 9,834,496 (mult of 16)
    const size_t BT_ELEMS = (size_t)NPT * NC * NO;         // 36,864 bf16
    const size_t need = XT_BYTES + BT_ELEMS * 2;

    if (ws_size >= need) {
        bf16_t* xt = (bf16_t*)d_ws;
        bf16_t* Bt = (bf16_t*)((char*)d_ws + XT_BYTES);
        prep_all<<<dim3(8 * 610), dim3(256), 0, stream>>>(x, W, xt, Bt);
        deform_mfma<<<dim3(NB * NH * NW / PIX), dim3(512), 0, stream>>>(xt, Bt, off, out);
    } else {
        deform_naive<<<dim3(NB * NH * NW), dim3(256), 0, stream>>>(x, W, off, out);
    }
}

// Round 17
// 38.183 us; speedup vs baseline: 1.5705x; 1.5705x over previous
//
#include <hip/hip_runtime.h>

// Deformable Conv2D, MFMA — coalesced gather + fused prep + 1 barrier/tap.
// (Verified best artifact: R10, 38.2 us total. Restored after 6 structural
// experiments — occupancy x2, 2-deep prefetch, register-direct A, wave-private
// staging, shuffle-params, producer/consumer — all measured neutral-to-worse.)
// x(8,64,96,96) f32, offset(8,18,96,96) f32, W(64,64,3,3) f32 -> out(8,64,96,96) f32.
// prep_all (one kernel, XCD-pinned by blk&7): interior fill of xt (bf16 NHWC padded),
//   border-only zero, Bt fragment build.
// deform_mfma: 1152 blocks x 256 thr; block = 64 px x 64 out. Per tap: in-reg bilinear
//   combine -> sA[n&1] (double buffer), params(n+1) by wave 0, ONE barrier, coalesced
//   8-lane/line gathers for tap n+1, verified MFMA. Verified LDS epilogue.

typedef __bf16 bf16_t;
typedef __bf16 bf16x8 __attribute__((ext_vector_type(8)));
typedef float  f32x4  __attribute__((ext_vector_type(4)));

#define NB 8
#define NC 64
#define NO 64
#define NH 96
#define NW 96
#define HP 98
#define NPT 9
#define PIX 64           // pixels per block
#define ASTR 72          // sA row stride in bf16

// ---------- parameter math (identical to round-0 verified version) ----------
struct DCParams { int u0, u1, v0, v1; float glt, grb, glb, grt; };

__device__ __forceinline__ DCParams dc_params(const float* __restrict__ off, int b, int i, int j, int n) {
    const int a = n / 3, b2 = n % 3;
    const float offx = off[((size_t)(b * 18 + n) * NH + i) * NW + j];
    const float offy = off[((size_t)(b * 18 + 9 + n) * NH + i) * NW + j];
    float px = (float)(i + a) + offx;
    float py = (float)(j + b2) + offy;
    const float fx = floorf(px), fy = floorf(py);
    const float x0 = fminf(fmaxf(fx, 0.f), 97.f);
    const float x1 = fminf(fmaxf(fx + 1.f, 0.f), 97.f);
    const float y0 = fminf(fmaxf(fy, 0.f), 97.f);
    const float y1 = fminf(fmaxf(fy + 1.f, 0.f), 97.f);
    px = (px < 1.f || px > 96.f) ? x0 : px;
    py = (py < 1.f || py > 96.f) ? y0 : py;
    const float wx0 = 1.f + x0 - px;
    const float wx1 = 1.f - x1 + px;
    const float wy0 = 1.f + y0 - py;
    const float wy1 = 1.f - y1 + py;
    DCParams p;
    p.u0 = (int)x0; p.u1 = (int)x1; p.v0 = (int)y0; p.v1 = (int)y1;
    p.glt = wx0 * wy0; p.grb = wx1 * wy1; p.glb = wx0 * wy1; p.grt = wx1 * wy0;
    return p;
}

// ---------- fused prep kernel (XCD-pinned: image b handled by blocks with blk&7==b) ----------
// grid = 8 * 610 blocks. r = blk>>3:
//   r <  576 : interior fill row (verified fill_xt16 math)
//   576..591 : border zero (3104 uint4 per image, 4096 slots)
//   592..609 : Bt build (b==0 blocks only; 4608 bf16x8 tasks)
__global__ __launch_bounds__(256) void prep_all(const float* __restrict__ x, const float* __restrict__ W,
                                                bf16_t* __restrict__ xt, bf16_t* __restrict__ Bt) {
    __shared__ float tile[64][17];
    const int blk = blockIdx.x;
    const int b = blk & 7;
    const int r = blk >> 3;
    const int t = threadIdx.x;

    if (r < 576) {                      // ---- interior fill (verified) ----
        const int jt = r % 6;
        const int i  = r / 6;
        const int j0 = jt * 16;
        {
            const int jj = t & 15, cq = t >> 4;
            #pragma unroll
            for (int rr = 0; rr < 4; ++rr) {
                const int c = cq * 4 + rr;
                tile[c][jj] = x[(((size_t)b * NC + c) * NH + i) * NW + j0 + jj];
            }
        }
        __syncthreads();
        {
            const int c = t & 63, jq = t >> 6;
            #pragma unroll
            for (int rr = 0; rr < 4; ++rr) {
                const int jj = jq * 4 + rr;
                xt[(((size_t)b * HP + (i + 1)) * HP + (j0 + jj + 1)) * NC + c] = (bf16_t)tile[c][jj];
            }
        }
    } else if (r < 592) {               // ---- border zero ----
        const int idx = (r - 576) * 256 + t;      // 0..4095; need 3104
        uint4* xt4 = (uint4*)xt;
        const size_t ib = (size_t)b * (HP * HP * NC / 8);
        const uint4 z = {0, 0, 0, 0};
        if (idx < 1568) {                          // rows u=0,97 (784 uint4 each)
            const int u   = (idx < 784) ? 0 : 97;
            const int pos = (idx < 784) ? idx : idx - 784;
            xt4[ib + (size_t)u * 784 + pos] = z;
        } else if (idx < 3104) {                   // cols v=0,97 for u=1..96 (8 uint4 each)
            const int k  = idx - 1568;
            const int v  = (k < 768) ? 0 : 97;
            const int kk = (k < 768) ? k : k - 768;
            const int u  = 1 + (kk >> 3), c8 = kk & 7;
            xt4[ib + (size_t)(u * HP + v) * 8 + c8] = z;
        }
    } else if (b == 0) {                // ---- Bt build (verified make_bt math) ----
        const int idx = (r - 592) * 256 + t;      // 0..4607
        const int l = idx & 63, frag = idx >> 6;
        const int nt = frag & 3, kk = (frag >> 2) & 1, n = frag >> 3;
        const int o  = nt * 16 + (l & 15);
        const int cb = kk * 32 + 8 * (l >> 4);
        bf16x8 v;
        #pragma unroll
        for (int j = 0; j < 8; ++j)
            v[j] = (bf16_t)W[(size_t)o * 576 + (cb + j) * 9 + n];
        *(bf16x8*)(Bt + (size_t)idx * 8) = v;
    }
}

// ---------- main kernel ----------
__device__ __forceinline__ void mfma_tap(const bf16_t* sAbuf, const bf16_t* __restrict__ Bt,
                                         int n, int w, int l, f32x4 acc[4]) {
    const int mrow = l & 15, khi = l >> 4;
    #pragma unroll
    for (int kk = 0; kk < 2; ++kk) {
        const bf16x8 bf = *(const bf16x8*)(Bt + (size_t)(((n * 2 + kk) * 4 + w)) * 512 + l * 8);
        #pragma unroll
        for (int mt = 0; mt < 4; ++mt) {
            const bf16x8 af = *(const bf16x8*)(sAbuf + (mt * 16 + mrow) * ASTR + kk * 32 + khi * 8);
            acc[mt] = __builtin_amdgcn_mfma_f32_16x16x32_bf16(af, bf, acc[mt], 0, 0, 0);
        }
    }
}

__global__ __launch_bounds__(256) void deform_mfma(const bf16_t* __restrict__ xt, const bf16_t* __restrict__ Bt,
                                                   const float* __restrict__ off, float* __restrict__ out) {
    // union: bf16 sA[2][64][72] (18432 B) main loop; f32 sO[64][68] (17408 B) epilogue
    __shared__ __align__(16) unsigned char smem[2 * PIX * ASTR * 2];
    bf16_t* sA = (bf16_t*)smem;
    float*  sO = (float*)smem;
    __shared__ __align__(16) int4   sI[2][PIX];   // corner element-offsets per pixel
    __shared__ __align__(16) float4 sG[2][PIX];   // corner weights per pixel

    const int t = threadIdx.x;
    const int l = t & 63;        // lane
    const int w = t >> 6;        // wave id: o-tile for MFMA, 16-pixel group for staging
    const int bid = blockIdx.x;
    const int b  = bid & 7;      // one batch image per XCD
    const int pb = (bid >> 3) * PIX;

    const int pl   = l >> 3;     // pixel-in-group low (0..7)
    const int slot = l & 7;      // channel slot: chans slot*8..slot*8+7
    const bf16_t* ibase = xt + (size_t)b * (HP * HP * NC) + slot * 8;

    f32x4 acc[4] = {};
    bf16x8 d[2][4];              // [q: px pl, pl+8][corner]

    // ---- prologue: params(tap 0) -> buf 0; gather tap 0 ----
    if (t < PIX) {
        const int pp = pb + t, ii = pp / 96, jj = pp - (pp / 96) * 96;
        const DCParams p = dc_params(off, b, ii, jj, 0);
        sI[0][t] = make_int4((p.u0 * HP + p.v0) * NC, (p.u1 * HP + p.v1) * NC,
                             (p.u0 * HP + p.v1) * NC, (p.u1 * HP + p.v0) * NC);
        sG[0][t] = make_float4(p.glt, p.grb, p.glb, p.grt);
    }
    __syncthreads();
    #pragma unroll
    for (int q = 0; q < 2; ++q) {
        const int px = w * 16 + pl + 8 * q;
        const int4 a4 = sI[0][px];
        d[q][0] = *(const bf16x8*)(ibase + a4.x);
        d[q][1] = *(const bf16x8*)(ibase + a4.y);
        d[q][2] = *(const bf16x8*)(ibase + a4.z);
        d[q][3] = *(const bf16x8*)(ibase + a4.w);
    }

    for (int n = 0; n < NPT; ++n) {
        bf16_t* buf = sA + (n & 1) * (PIX * ASTR);
        // ---- combine in-register -> sA[n&1] (verified layout) ----
        #pragma unroll
        for (int q = 0; q < 2; ++q) {
            const int px = w * 16 + pl + 8 * q;
            const float4 g = sG[n & 1][px];
            bf16x8 rv;
            #pragma unroll
            for (int e = 0; e < 8; ++e) {
                const float v = g.x * (float)d[q][0][e] + g.y * (float)d[q][1][e]
                              + g.z * (float)d[q][2][e] + g.w * (float)d[q][3][e];
                rv[e] = (bf16_t)v;
            }
            *(bf16x8*)(buf + px * ASTR + slot * 8) = rv;
        }
        // ---- params for tap n+1 (wave 0) -> sI/sG[(n+1)&1] ----
        if (n + 1 < NPT && t < PIX) {
            const int pp = pb + t, ii = pp / 96, jj = pp - (pp / 96) * 96;
            const DCParams p = dc_params(off, b, ii, jj, n + 1);
            sI[(n + 1) & 1][t] = make_int4((p.u0 * HP + p.v0) * NC, (p.u1 * HP + p.v1) * NC,
                                           (p.u0 * HP + p.v1) * NC, (p.u1 * HP + p.v0) * NC);
            sG[(n + 1) & 1][t] = make_float4(p.glt, p.grb, p.glb, p.grt);
        }
        __syncthreads();             // sA[n&1] + sI/sG[(n+1)&1] visible; prev-buf readers done
        // ---- issue next-tap coalesced gathers (retire under MFMA) ----
        if (n + 1 < NPT) {
            #pragma unroll
            for (int q = 0; q < 2; ++q) {
                const int px = w * 16 + pl + 8 * q;
                const int4 a4 = sI[(n + 1) & 1][px];
                d[q][0] = *(const bf16x8*)(ibase + a4.x);
                d[q][1] = *(const bf16x8*)(ibase + a4.y);
                d[q][2] = *(const bf16x8*)(ibase + a4.z);
                d[q][3] = *(const bf16x8*)(ibase + a4.w);
            }
        }
        // ---- MFMA (verified) ----
        mfma_tap(buf, Bt, n, w, l, acc);
        // next iteration writes the other sA buffer: no second barrier needed
    }

    __syncthreads();                             // final sA reads retired before sO reuse

    // ---- epilogue (verified): acc -> sO[o][pix] -> coalesced float4 stores ----
    const int orow = w * 16 + (l & 15);
    #pragma unroll
    for (int mt = 0; mt < 4; ++mt)
        #pragma unroll
        for (int r = 0; r < 4; ++r)
            sO[orow * 68 + mt * 16 + (l >> 4) * 4 + r] = acc[mt][r];
    __syncthreads();

    const int o = t >> 2, q = t & 3;
    float4* dst = (float4*)(out + ((size_t)(b * NO + o)) * (NH * NW) + pb + q * 16);
    const float* src = sO + o * 68 + q * 16;
    #pragma unroll
    for (int k2 = 0; k2 < 4; ++k2) dst[k2] = ((const float4*)src)[k2];
}

// ---------- naive fallback (no workspace needed) ----------
__global__ __launch_bounds__(256) void deform_naive(const float* __restrict__ x, const float* __restrict__ W,
                                                    const float* __restrict__ off, float* __restrict__ out) {
    __shared__ float sv[576];
    __shared__ DCParams sp[NPT];
    const int t = threadIdx.x;
    const int P = blockIdx.x;
    const int b = P / (NH * NW), pp = P - b * (NH * NW);
    const int i = pp / 96, j = pp - (pp / 96) * 96;
    if (t < NPT) sp[t] = dc_params(off, b, i, j, t);
    __syncthreads();
    for (int k = t; k < 576; k += 256) {
        const int c = k / 9, n = k - c * 9;
        const DCParams p = sp[n];
        const float* xb = x + ((size_t)(b * NC + c)) * (NH * NW);
        const float vlt = (p.u0 >= 1 && p.u0 <= 96 && p.v0 >= 1 && p.v0 <= 96) ? xb[(p.u0 - 1) * 96 + (p.v0 - 1)] : 0.f;
        const float vrb = (p.u1 >= 1 && p.u1 <= 96 && p.v1 >= 1 && p.v1 <= 96) ? xb[(p.u1 - 1) * 96 + (p.v1 - 1)] : 0.f;
        const float vlb = (p.u0 >= 1 && p.u0 <= 96 && p.v1 >= 1 && p.v1 <= 96) ? xb[(p.u0 - 1) * 96 + (p.v1 - 1)] : 0.f;
        const float vrt = (p.u1 >= 1 && p.u1 <= 96 && p.v0 >= 1 && p.v0 <= 96) ? xb[(p.u1 - 1) * 96 + (p.v0 - 1)] : 0.f;
        sv[k] = p.glt * vlt + p.grb * vrb + p.glb * vlb + p.grt * vrt;
    }
    __syncthreads();
    if (t < NO) {
        const float* wrow = W + (size_t)t * 576;
        float acc = 0.f;
        for (int k = 0; k < 576; ++k) acc += sv[k] * wrow[k];
        out[((size_t)(b * NO + t)) * (NH * NW) + pp] = acc;
    }
}

extern "C" void kernel_launch(void* const* d_in, const int* in_sizes, int n_in,
                              void* d_out, int out_size, void* d_ws, size_t ws_size,
                              hipStream_t stream) {
    const float* x   = (const float*)d_in[0];
    const float* off = (const float*)d_in[1];
    const float* W   = (const float*)d_in[2];
    float* out = (float*)d_out;

    const size_t XT_ELEMS = (size_t)NB * HP * HP * NC;     // 4,917,248 bf16
    const size_t XT_BYTES = XT_ELEMS * 2;                  // 9,834,496 (mult of 16)
    const size_t BT_ELEMS = (size_t)NPT * NC * NO;         // 36,864 bf16
    const size_t need = XT_BYTES + BT_ELEMS * 2;

    if (ws_size >= need) {
        bf16_t* xt = (bf16_t*)d_ws;
        bf16_t* Bt = (bf16_t*)((char*)d_ws + XT_BYTES);
        prep_all<<<dim3(8 * 610), dim3(256), 0, stream>>>(x, W, xt, Bt);
        deform_mfma<<<dim3(NB * NH * NW / PIX), dim3(256), 0, stream>>>(xt, Bt, off, out);
    } else {
        deform_naive<<<dim3(NB * NH * NW), dim3(256), 0, stream>>>(x, W, off, out);
    }
}